// Round 8
// baseline (112.429 us; speedup 1.0000x reference)
//
#include <hip/hip_runtime.h>
#include <stdint.h>

typedef uint16_t u16;
typedef __attribute__((ext_vector_type(4))) float f32x4;
typedef __attribute__((ext_vector_type(8))) short short8;
typedef __attribute__((ext_vector_type(4))) float float4v;
typedef __attribute__((ext_vector_type(4))) uint16_t u16x4;
typedef __attribute__((ext_vector_type(8))) uint16_t u16x8;

#define DIMQ 1024
#define BATCH 8192
#define KDIM 1024
#define NDIM 1024
#define NBLK 512

#define RDL(v, l) __int_as_float(__builtin_amdgcn_readlane(__float_as_int(v), (l)))

__device__ __forceinline__ u16 f2bf(float f) {
  uint32_t u = __float_as_uint(f);
  u += 0x7fffu + ((u >> 16) & 1u);
  return (u16)(u >> 16);
}

// cross-lane xor exchange; DPP (VALU pipe) for masks 1,2,8; ds_swizzle for 4,16;
// bpermute-based __shfl_xor only for 32.  (verified R4/R5)
template<int MASK>
__device__ __forceinline__ float lane_xor(float x) {
  if constexpr (MASK == 1)
    return __int_as_float(__builtin_amdgcn_update_dpp(0, __float_as_int(x), 0xB1, 0xF, 0xF, true));
  else if constexpr (MASK == 2)
    return __int_as_float(__builtin_amdgcn_update_dpp(0, __float_as_int(x), 0x4E, 0xF, 0xF, true));
  else if constexpr (MASK == 8)
    return __int_as_float(__builtin_amdgcn_update_dpp(0, __float_as_int(x), 0x128, 0xF, 0xF, true));
  else if constexpr (MASK == 4)
    return __int_as_float(__builtin_amdgcn_ds_swizzle(__float_as_int(x), 0x101F));
  else if constexpr (MASK == 16)
    return __int_as_float(__builtin_amdgcn_ds_swizzle(__float_as_int(x), 0x401F));
  else
    return __shfl_xor(x, 32, 64);
}

// one cross-lane gate on 16 regs: batched partner fetch, then FMAs (verified R3-R5)
template<int MASK>
__device__ __forceinline__ void lane_gate(float* ar, float* ai, int lane,
    float u00r, float u00i, float u01r, float u01i,
    float u10r, float u10i, float u11r, float u11i) {
  bool hi = (lane & MASK) != 0;
  float cmr = hi ? u11r : u00r, cmi = hi ? u11i : u00i;
  float cor = hi ? u10r : u01r, coi = hi ? u10i : u01i;
  float otr[16], oti[16];
#pragma unroll
  for (int r = 0; r < 16; ++r) otr[r] = lane_xor<MASK>(ar[r]);
#pragma unroll
  for (int r = 0; r < 16; ++r) oti[r] = lane_xor<MASK>(ai[r]);
#pragma unroll
  for (int r = 0; r < 16; ++r) {
    float nr = cmr*ar[r] - cmi*ai[r] + cor*otr[r] - coi*oti[r];
    float ni = cmr*ai[r] + cmi*ar[r] + cor*oti[r] + coi*otr[r];
    ar[r] = nr; ai[r] = ni;
  }
}

// complex 2x2 layout: {00r,00i, 01r,01i, 10r,10i, 11r,11i}
__device__ inline void cmul2x2(float* O, const float* A, const float* B) {
  for (int r = 0; r < 2; ++r)
    for (int c = 0; c < 2; ++c) {
      float re = 0.f, im = 0.f;
      for (int j = 0; j < 2; ++j) {
        float ar = A[(r*2+j)*2], ai = A[(r*2+j)*2+1];
        float br = B[(j*2+c)*2], bi = B[(j*2+c)*2+1];
        re += ar*br - ai*bi;
        im += ar*bi + ai*br;
      }
      O[(r*2+c)*2]   = re;
      O[(r*2+c)*2+1] = im;
    }
}
__device__ inline void mk_rx(float* m, float t) {
  float s, c; sincosf(0.5f*t, &s, &c);
  m[0]=c; m[1]=0; m[2]=0; m[3]=-s; m[4]=0; m[5]=-s; m[6]=c; m[7]=0;
}
__device__ inline void mk_ry(float* m, float t) {
  float s, c; sincosf(0.5f*t, &s, &c);
  m[0]=c; m[1]=0; m[2]=-s; m[3]=0; m[4]=s; m[5]=0; m[6]=c; m[7]=0;
}
__device__ inline void mk_rz(float* m, float t) {
  float s, c; sincosf(0.5f*t, &s, &c);
  m[0]=c; m[1]=-s; m[2]=0; m[3]=0; m[4]=0; m[5]=0; m[6]=c; m[7]=s;
}

// ONE kernel, 512 blocks x 256 threads, all co-resident (VGPR<=256 -> >=2 blk/CU).
// Phase A: waves 0,1 build basis states d=bid*2+wv (R5's verified 1-wave body);
//          waves 2,3 normalize 8 rows each (x fp32 -> bf16).
// Spin-barrier: device-scope atomic counter + acquire spin (Guideline 16).
// Phase B: 128x128 bf16 MFMA gemm tile bid (verified m97-structure body).
__global__ __launch_bounds__(256, 2) void mega(const float* __restrict__ x,
                                               const float* __restrict__ w,
                                               u16* __restrict__ Abf,
                                               u16* __restrict__ Bmat,
                                               float* __restrict__ C,
                                               unsigned* __restrict__ ctr) {
  __shared__ u16 As[128*32];
  __shared__ u16 Bs[128*32];
  const int bid = blockIdx.x, tid = threadIdx.x;
  const int lane = tid & 63, wv = tid >> 6;

  // ================= Phase A =================
  if (wv < 2) {
    // ---- build basis state d ----
    const int d = bid*2 + wv;
    float O0, O1, O2, O3, O4, O5, O6, O7;
    {
      float A[8], B[8], Cg[8], T8[8], O[8];
      int t = lane;
      if (t < 50) {
        if (t < 10) {
          mk_ry(A, -w[120 + t]);
          mk_rz(B, -w[130 + t]);
          mk_ry(Cg, -w[140 + t]);
        } else {
          int s = (t - 10) / 10, q = (t - 10) % 10, l = 3 - s;
          mk_rx(A, -w[l*30 + q]);
          mk_ry(B, -w[l*30 + 10 + q]);
          mk_rz(Cg, -w[l*30 + 20 + q]);
        }
        cmul2x2(T8, A, B);
        cmul2x2(O, T8, Cg);
      } else {
#pragma unroll
        for (int j = 0; j < 8; ++j) O[j] = 0.f;
      }
      O0=O[0]; O1=O[1]; O2=O[2]; O3=O[3]; O4=O[4]; O5=O[5]; O6=O[6]; O7=O[7];
    }

    // fixed source-lane map for the CNOT-ring permutation (verified R3)
    int b0 = __builtin_popcount(lane & 0x3f) & 1;   // PL
    int b1 = __builtin_popcount(lane & 0x3e) & 1;
    int b2 = __builtin_popcount(lane & 0x3c) & 1;
    int b3 = __builtin_popcount(lane & 0x38) & 1;
    int b4 = __builtin_popcount(lane & 0x30) & 1;
    int b5 = b0 ^ (lane >> 5);                      // PL ^ L5
    int lsrcE = b0 | (b1<<1) | (b2<<2) | (b3<<3) | (b4<<4) | (b5<<5);
    int lsrcO = lsrcE ^ 32;
    bool oddlane = lane & 1;

    float ar[16], ai[16];
#pragma unroll
    for (int r = 0; r < 16; ++r) {
      ar[r] = ((lane << 4) + r == d) ? 1.0f : 0.0f;
      ai[r] = 0.0f;
    }

#pragma clang loop unroll(disable)
    for (int stage = 0; stage < 5; ++stage) {
      if (stage) {
        static const int T[16] = {0,1,3,2,7,6,4,5,15,14,12,13,8,9,11,10};
        float pr_[16], pi_[16];
#pragma unroll
        for (int r = 0; r < 16; ++r) {
          pr_[r] = oddlane ? ar[T[r]^15] : ar[T[r]];
          pi_[r] = oddlane ? ai[T[r]^15] : ai[T[r]];
        }
#pragma unroll
        for (int r = 0; r < 16; ++r) {
          int src = (__builtin_popcount((unsigned)r) & 1) ? lsrcO : lsrcE;
          ar[r] = __shfl(pr_[r], src, 64);
          ai[r] = __shfl(pi_[r], src, 64);
        }
      }
      const int gbase = stage * 10;
      { int g = gbase + 0; lane_gate<32>(ar, ai, lane, RDL(O0,g),RDL(O1,g),RDL(O2,g),RDL(O3,g),RDL(O4,g),RDL(O5,g),RDL(O6,g),RDL(O7,g)); }
      { int g = gbase + 1; lane_gate<16>(ar, ai, lane, RDL(O0,g),RDL(O1,g),RDL(O2,g),RDL(O3,g),RDL(O4,g),RDL(O5,g),RDL(O6,g),RDL(O7,g)); }
      { int g = gbase + 2; lane_gate< 8>(ar, ai, lane, RDL(O0,g),RDL(O1,g),RDL(O2,g),RDL(O3,g),RDL(O4,g),RDL(O5,g),RDL(O6,g),RDL(O7,g)); }
      { int g = gbase + 3; lane_gate< 4>(ar, ai, lane, RDL(O0,g),RDL(O1,g),RDL(O2,g),RDL(O3,g),RDL(O4,g),RDL(O5,g),RDL(O6,g),RDL(O7,g)); }
      { int g = gbase + 4; lane_gate< 2>(ar, ai, lane, RDL(O0,g),RDL(O1,g),RDL(O2,g),RDL(O3,g),RDL(O4,g),RDL(O5,g),RDL(O6,g),RDL(O7,g)); }
      { int g = gbase + 5; lane_gate< 1>(ar, ai, lane, RDL(O0,g),RDL(O1,g),RDL(O2,g),RDL(O3,g),RDL(O4,g),RDL(O5,g),RDL(O6,g),RDL(O7,g)); }
#pragma unroll
      for (int q = 6; q < 10; ++q) {
        const int p = 9 - q;
        int g = gbase + q;
        float u00r=RDL(O0,g), u00i=RDL(O1,g), u01r=RDL(O2,g), u01i=RDL(O3,g);
        float u10r=RDL(O4,g), u10i=RDL(O5,g), u11r=RDL(O6,g), u11i=RDL(O7,g);
#pragma unroll
        for (int h = 0; h < 8; ++h) {
          int r0 = ((h >> p) << (p+1)) | (h & ((1 << p) - 1));
          int r1 = r0 | (1 << p);
          float a0r = ar[r0], a0i = ai[r0], a1r = ar[r1], a1i = ai[r1];
          ar[r0] = u00r*a0r - u00i*a0i + u01r*a1r - u01i*a1i;
          ai[r0] = u00r*a0i + u00i*a0r + u01r*a1i + u01i*a1r;
          ar[r1] = u10r*a0r - u10i*a0i + u11r*a1r - u11i*a1i;
          ai[r1] = u10r*a0i + u10i*a0r + u11r*a1i + u11i*a1r;
        }
      }
    }

    u16x8 v0, v1;
#pragma unroll
    for (int r = 0; r < 8; ++r) v0[r] = f2bf(ar[r]);
#pragma unroll
    for (int r = 0; r < 8; ++r) v1[r] = f2bf(ar[8 + r]);
    u16* row = Bmat + (size_t)d * DIMQ + lane * 16;
    *(u16x8*)row = v0;
    *(u16x8*)(row + 8) = v1;
  } else {
    // ---- normalize 8 rows (x fp32 -> bf16) ----
    int nw = bid*2 + (wv - 2);
    for (int it = 0; it < 8; ++it) {
      int rowi = nw*8 + it;
      const float* xr = x + (size_t)rowi * DIMQ;
      float4v v[4];
      float ss = 0.f;
#pragma unroll
      for (int j = 0; j < 4; ++j) {
        v[j] = *(const float4v*)(xr + j*256 + lane*4);
        ss += v[j][0]*v[j][0] + v[j][1]*v[j][1] + v[j][2]*v[j][2] + v[j][3]*v[j][3];
      }
#pragma unroll
      for (int off = 32; off; off >>= 1) ss += __shfl_xor(ss, off, 64);
      float inv = 1.0f / fmaxf(sqrtf(ss), 1e-12f);
      u16* orow = Abf + (size_t)rowi * DIMQ;
#pragma unroll
      for (int j = 0; j < 4; ++j) {
        u16x4 o;
#pragma unroll
        for (int e = 0; e < 4; ++e) o[e] = f2bf(v[j][e] * inv);
        *(u16x4*)(orow + j*256 + lane*4) = o;
      }
    }
  }

  // ============ device-scope spin barrier ============
  __syncthreads();                 // drains this block's stores (vmcnt before s_barrier)
  if (tid == 0) {
    __threadfence();               // flush to device scope (wbl2)
    atomicAdd(ctr, 1u);            // device-scope by default
    while (__hip_atomic_load(ctr, __ATOMIC_ACQUIRE, __HIP_MEMORY_SCOPE_AGENT) < NBLK)
      __builtin_amdgcn_s_sleep(2);
  }
  __syncthreads();

  // ================= Phase B: gemm tile =================
  int nid = ((bid & 7) << 6) | (bid >> 3);   // XCD swizzle, 512 = 8*64
  int bm = nid >> 3, bn = nid & 7;
  size_t aBase = (size_t)bm * 128 * KDIM;
  size_t bBase = (size_t)bn * 128 * KDIM;
  int r0 = wv*16 + (lane >> 2);
  int c0 = (lane & 3) * 8;
  int wm = (wv >> 1) * 64, wn = (wv & 1) * 64;
  int la = lane & 15, lk = (lane >> 4) * 8;
  f32x4 acc[4][4];
#pragma unroll
  for (int m = 0; m < 4; ++m)
#pragma unroll
    for (int n = 0; n < 4; ++n) acc[m][n] = (f32x4){0.f, 0.f, 0.f, 0.f};

  for (int k0 = 0; k0 < KDIM; k0 += 32) {
    __syncthreads();
#pragma unroll
    for (int j = 0; j < 2; ++j) {
      __builtin_amdgcn_global_load_lds(
          (const __attribute__((address_space(1))) void*)(Abf + aBase + (size_t)(j*64 + r0)*KDIM + k0 + c0),
          (__attribute__((address_space(3))) void*)((char*)As + j*4096 + wv*1024), 16, 0, 0);
      __builtin_amdgcn_global_load_lds(
          (const __attribute__((address_space(1))) void*)(Bmat + bBase + (size_t)(j*64 + r0)*KDIM + k0 + c0),
          (__attribute__((address_space(3))) void*)((char*)Bs + j*4096 + wv*1024), 16, 0, 0);
    }
    __syncthreads();
    short8 af[4], bf[4];
#pragma unroll
    for (int m = 0; m < 4; ++m) af[m] = *(const short8*)&As[(wm + m*16 + la)*32 + lk];
#pragma unroll
    for (int n = 0; n < 4; ++n) bf[n] = *(const short8*)&Bs[(wn + n*16 + la)*32 + lk];
#pragma unroll
    for (int m = 0; m < 4; ++m)
#pragma unroll
      for (int n = 0; n < 4; ++n)
        acc[m][n] = __builtin_amdgcn_mfma_f32_16x16x32_bf16(af[m], bf[n], acc[m][n], 0, 0, 0);
  }

  int orow0 = bm*128 + wm + (lane >> 4)*4;
  int ocol0 = bn*128 + wn + la;
#pragma unroll
  for (int m = 0; m < 4; ++m)
#pragma unroll
    for (int n = 0; n < 4; ++n)
#pragma unroll
      for (int j = 0; j < 4; ++j)
        C[(size_t)(orow0 + m*16 + j)*NDIM + ocol0 + n*16] = acc[m][n][j];
}

extern "C" void kernel_launch(void* const* d_in, const int* in_sizes, int n_in,
                              void* d_out, int out_size, void* d_ws, size_t ws_size,
                              hipStream_t stream) {
  const float* x = (const float*)d_in[0];
  const float* w = (const float*)d_in[1];
  float* out = (float*)d_out;
  char* ws = (char*)d_ws;
  unsigned* ctr = (unsigned*)ws;                             // 4 B (zeroed below)
  u16* Bmat = (u16*)(ws + 4096);                             // 2 MB
  u16* Abf  = (u16*)(ws + 4096 + 2*1024*1024);               // 16 MB

  hipMemsetAsync(ctr, 0, 4096, stream);
  mega<<<NBLK, 256, 0, stream>>>(x, w, Abf, Bmat, out, ctr);
}